// Round 1
// baseline (2913.756 us; speedup 1.0000x reference)
//
#include <hip/hip_runtime.h>
#include <cstddef>
#include <cstdint>

#define N_NODES 102400
#define N_EDGES 3276800
#define N_GRAPHS 1024

// ---------------------------------------------------------------------------
// CSR build: degree (by src, weighted) + in-degree count (by dst)
// ---------------------------------------------------------------------------
__global__ void k_edge_deg(const int* __restrict__ src, const int* __restrict__ dst,
                           const float* __restrict__ w, float* __restrict__ deg,
                           int* __restrict__ cnt) {
    int e = blockIdx.x * blockDim.x + threadIdx.x;
    if (e >= N_EDGES) return;
    atomicAdd(&deg[src[e]], w[e]);
    atomicAdd(&cnt[dst[e]], 1);
}

__global__ void k_dinv(float* __restrict__ deg) {
    int n = blockIdx.x * blockDim.x + threadIdx.x;
    if (n >= N_NODES) return;
    float d = deg[n];
    deg[n] = d > 0.f ? rsqrtf(d) : 0.f;
}

// 3-kernel exclusive scan of cnt[N_NODES] -> rowp[N_NODES+1]
__global__ void k_scan1(const int* __restrict__ cnt, int* __restrict__ bsum) {
    __shared__ int s[256];
    int t = threadIdx.x, b = blockIdx.x;
    int base = b * 1024 + t * 4;
    int v = cnt[base] + cnt[base + 1] + cnt[base + 2] + cnt[base + 3];
    s[t] = v; __syncthreads();
    for (int o = 128; o > 0; o >>= 1) {
        if (t < o) s[t] += s[t + o];
        __syncthreads();
    }
    if (t == 0) bsum[b] = s[0];
}

__global__ void k_scan2(const int* __restrict__ bsum, int* __restrict__ boff,
                        int* __restrict__ rowp) {
    if (threadIdx.x == 0 && blockIdx.x == 0) {
        int run = 0;
        for (int i = 0; i < 100; i++) { boff[i] = run; run += bsum[i]; }
        rowp[N_NODES] = run;
    }
}

__global__ void k_scan3(const int* __restrict__ cnt, const int* __restrict__ boff,
                        int* __restrict__ rowp) {
    __shared__ int ts[256];
    int t = threadIdx.x, b = blockIdx.x;
    int base = b * 1024 + t * 4;
    int v0 = cnt[base], v1 = cnt[base + 1], v2 = cnt[base + 2], v3 = cnt[base + 3];
    int s = v0 + v1 + v2 + v3;
    ts[t] = s; __syncthreads();
    for (int o = 1; o < 256; o <<= 1) {
        int x = (t >= o) ? ts[t - o] : 0;
        __syncthreads();
        ts[t] += x;
        __syncthreads();
    }
    int excl = (t == 0 ? 0 : ts[t - 1]) + boff[b];
    rowp[base]     = excl;
    rowp[base + 1] = excl + v0;
    rowp[base + 2] = excl + v0 + v1;
    rowp[base + 3] = excl + v0 + v1 + v2;
}

__global__ void k_scatter(const int* __restrict__ src, const int* __restrict__ dst,
                          const float* __restrict__ attr, const float* __restrict__ dinv,
                          const int* __restrict__ rowp, int* __restrict__ fill,
                          int* __restrict__ ccol, float* __restrict__ cw) {
    int e = blockIdx.x * blockDim.x + threadIdx.x;
    if (e >= N_EDGES) return;
    int s = src[e], d = dst[e];
    float w = -dinv[s] * attr[e] * dinv[d];
    int p = atomicAdd(&fill[d], 1);
    int idx = rowp[d] + p;
    ccol[idx] = s;
    cw[idx] = w;
}

__global__ void k_wsub(const float* __restrict__ a, const float* __restrict__ b,
                       float* __restrict__ o, int n) {
    int i = blockIdx.x * blockDim.x + threadIdx.x;
    if (i < n) o[i] = a[i] - b[i];
}

// ---------------------------------------------------------------------------
// SpMM: Y[n,:] = scale * sum_e w_e * X[col_e,:]   (wave per node, 4 waves/block)
// ---------------------------------------------------------------------------
template <int F>
__global__ void k_spmm(const int* __restrict__ rowp, const int* __restrict__ ccol,
                       const float* __restrict__ cw, const float* __restrict__ X,
                       float* __restrict__ Y, float scale) {
    int node = blockIdx.x * (blockDim.x >> 6) + (threadIdx.x >> 6);
    int lane = threadIdx.x & 63;
    if (node >= N_NODES) return;
    int s = rowp[node], e = rowp[node + 1];
    if (F == 128) {
        const float2* X2 = reinterpret_cast<const float2*>(X);
        float2 acc = make_float2(0.f, 0.f);
        for (int i = s; i < e; i++) {
            int c = ccol[i];
            float w = cw[i];
            float2 v = X2[(size_t)c * 64 + lane];
            acc.x = fmaf(w, v.x, acc.x);
            acc.y = fmaf(w, v.y, acc.y);
        }
        float2* Yp = reinterpret_cast<float2*>(Y);
        Yp[(size_t)node * 64 + lane] = make_float2(acc.x * scale, acc.y * scale);
    } else {
        float acc = 0.f;
        for (int i = s; i < e; i++) {
            int c = ccol[i];
            float w = cw[i];
            acc = fmaf(w, X[(size_t)c * 64 + lane], acc);
        }
        Y[(size_t)node * 64 + lane] = acc * scale;
    }
}

// ---------------------------------------------------------------------------
// GEMM: out[n, colOff+j] (+)= sum_i X[n,i] * W[i, colOff+j]  (+bias, relu)
// 128 nodes/block, thread-per-node, acc[64] in VGPRs, W via uniform s_loads.
// out0 holds cols [0,64), out1 cols [64,128) (both stride 64).
// ---------------------------------------------------------------------------
template <int FIN, int FTOT>
__global__ __launch_bounds__(128) void k_gemm(const float* __restrict__ X,
                                              const float* __restrict__ W,
                                              const float* __restrict__ bias,
                                              float* __restrict__ out0,
                                              float* __restrict__ out1,
                                              int accumulate, int relu) {
    constexpr int KC = 16;
    __shared__ float Xs[KC][129];
    int t = threadIdx.x;
    int nodeBase = blockIdx.x * 128;
    int colOff = blockIdx.y * 64;
    float* outp = blockIdx.y ? out1 : out0;

    float acc[64];
#pragma unroll
    for (int j = 0; j < 64; j++) acc[j] = 0.f;

    int kk = t & 15, nl0 = t >> 4;
    for (int k0 = 0; k0 < FIN; k0 += KC) {
        __syncthreads();
#pragma unroll
        for (int r = 0; r < 16; r++) {
            int nl = nl0 + r * 8;
            Xs[kk][nl] = X[(size_t)(nodeBase + nl) * FIN + k0 + kk];
        }
        __syncthreads();
#pragma unroll
        for (int i = 0; i < KC; i++) {
            float xv = Xs[i][t];
            const float* wr = W + (size_t)(k0 + i) * FTOT + colOff;
#pragma unroll
            for (int j = 0; j < 64; j++) acc[j] = fmaf(xv, wr[j], acc[j]);
        }
    }

    size_t obase = (size_t)(nodeBase + t) * 64;
    if (accumulate) {
        if (relu) {
#pragma unroll
            for (int j = 0; j < 64; j++) {
                float v = acc[j] + outp[obase + j] + bias[colOff + j];
                outp[obase + j] = fmaxf(v, 0.f);
            }
        } else {
#pragma unroll
            for (int j = 0; j < 64; j++) outp[obase + j] = acc[j] + outp[obase + j];
        }
    } else {
#pragma unroll
        for (int j = 0; j < 64; j++) outp[obase + j] = acc[j];
    }
}

// ---------------------------------------------------------------------------
// Pooling: atomic accumulate per graph; final linear 128->2 (wave per graph)
// ---------------------------------------------------------------------------
__global__ void k_pool(const int* __restrict__ batch, const float* __restrict__ h3a,
                       const float* __restrict__ h3b, float* __restrict__ pooled,
                       float* __restrict__ gcnt) {
    int n = blockIdx.x;
    int t = threadIdx.x; // 128 threads
    int g = batch[n];
    float v = (t < 64) ? h3a[(size_t)n * 64 + t] : h3b[(size_t)n * 64 + (t - 64)];
    atomicAdd(&pooled[(size_t)g * 128 + t], v);
    if (t == 0) atomicAdd(&gcnt[g], 1.0f);
}

__global__ void k_final(const float* __restrict__ pooled, const float* __restrict__ gcnt,
                        const float* __restrict__ lin_w, const float* __restrict__ lin_b,
                        float* __restrict__ out) {
    int g = blockIdx.x * 4 + (threadIdx.x >> 6);
    int lane = threadIdx.x & 63;
    if (g >= N_GRAPHS) return;
    float inv = 1.f / fmaxf(gcnt[g], 1.f);
    float v0 = pooled[(size_t)g * 128 + lane] * inv;
    float v1 = pooled[(size_t)g * 128 + 64 + lane] * inv;
    float p0 = v0 * lin_w[lane * 2 + 0] + v1 * lin_w[(lane + 64) * 2 + 0];
    float p1 = v0 * lin_w[lane * 2 + 1] + v1 * lin_w[(lane + 64) * 2 + 1];
    for (int o = 32; o > 0; o >>= 1) {
        p0 += __shfl_down(p0, o);
        p1 += __shfl_down(p1, o);
    }
    if (lane == 0) {
        out[g * 2 + 0] = p0 + lin_b[0];
        out[g * 2 + 1] = p1 + lin_b[1];
    }
}

// ---------------------------------------------------------------------------
extern "C" void kernel_launch(void* const* d_in, const int* in_sizes, int n_in,
                              void* d_out, int out_size, void* d_ws, size_t ws_size,
                              hipStream_t stream) {
    const float* x     = (const float*)d_in[0];
    const int*   src   = (const int*)d_in[1];
    const int*   dst   = src + N_EDGES;
    const float* eattr = (const float*)d_in[2];
    const int*   batch = (const int*)d_in[3];
    const float* w1    = (const float*)d_in[4];
    const float* b1    = (const float*)d_in[5];
    const float* w2    = (const float*)d_in[6];
    const float* b2    = (const float*)d_in[7];
    const float* w3    = (const float*)d_in[8];
    const float* b3    = (const float*)d_in[9];
    const float* lin_w = (const float*)d_in[10];
    const float* lin_b = (const float*)d_in[11];
    float* out = (float*)d_out;

    char* ws = (char*)d_ws;
    size_t off = 0;
    auto alloc = [&](size_t bytes) -> char* {
        char* p = ws + off;
        off += (bytes + 255) & ~(size_t)255;
        return p;
    };
    float* deg    = (float*)alloc((size_t)N_NODES * 4);        // becomes dinv in-place
    int*   cnt    = (int*)  alloc((size_t)N_NODES * 4);
    int*   fill   = (int*)  alloc((size_t)N_NODES * 4);
    int*   rowp   = (int*)  alloc((size_t)(N_NODES + 1) * 4);
    int*   bsum   = (int*)  alloc(128 * 4);
    int*   boff   = (int*)  alloc(128 * 4);
    float* wc1    = (float*)alloc(128 * 64 * 4);
    float* wc2    = (float*)alloc(64 * 64 * 4);
    float* wc3    = (float*)alloc(64 * 128 * 4);
    float* pooled = (float*)alloc((size_t)(N_GRAPHS * 128 + N_GRAPHS) * 4);
    float* gcnt   = pooled + (size_t)N_GRAPHS * 128;
    int*   ccol   = (int*)  alloc((size_t)N_EDGES * 4);
    float* cw     = (float*)alloc((size_t)N_EDGES * 4);
    float* bufA   = (float*)alloc((size_t)N_NODES * 128 * 4);
    float* bufB   = (float*)alloc((size_t)N_NODES * 128 * 4);
    float* H1     = (float*)alloc((size_t)N_NODES * 64 * 4);
    float* H2     = (float*)alloc((size_t)N_NODES * 64 * 4);
    // layer-3 output (N x 128) split across the unused upper halves of bufA/bufB
    float* H3a = bufA + (size_t)N_NODES * 64; // cols [0,64)
    float* H3b = bufB + (size_t)N_NODES * 64; // cols [64,128)

    // deg/cnt/fill are contiguous (each N*4 = 409600 bytes, 256-aligned)
    hipMemsetAsync(deg, 0, (size_t)N_NODES * 4 * 3, stream);
    hipMemsetAsync(pooled, 0, (size_t)(N_GRAPHS * 128 + N_GRAPHS) * 4, stream);

    // CSR build
    k_edge_deg<<<N_EDGES / 256, 256, 0, stream>>>(src, dst, eattr, deg, cnt);
    k_dinv<<<N_NODES / 256, 256, 0, stream>>>(deg);
    k_scan1<<<100, 256, 0, stream>>>(cnt, bsum);
    k_scan2<<<1, 64, 0, stream>>>(bsum, boff, rowp);
    k_scan3<<<100, 256, 0, stream>>>(cnt, boff, rowp);
    k_scatter<<<N_EDGES / 256, 256, 0, stream>>>(src, dst, eattr, deg, rowp, fill, ccol, cw);

    // combined weights W0 - W2 per layer
    k_wsub<<<32, 256, 0, stream>>>(w1, w1 + 2 * 128 * 64, wc1, 128 * 64);
    k_wsub<<<16, 256, 0, stream>>>(w2, w2 + 2 * 64 * 64, wc2, 64 * 64);
    k_wsub<<<32, 256, 0, stream>>>(w3, w3 + 2 * 64 * 128, wc3, 64 * 128);

    // Layer 1: 128 -> 64
    k_gemm<128, 64><<<dim3(800, 1), 128, 0, stream>>>(x, wc1, nullptr, H1, H1, 0, 0);
    k_spmm<128><<<N_NODES / 4, 256, 0, stream>>>(rowp, ccol, cw, x, bufA, 1.f);
    k_gemm<128, 64><<<dim3(800, 1), 128, 0, stream>>>(bufA, w1 + 128 * 64, nullptr, H1, H1, 1, 0);
    k_spmm<128><<<N_NODES / 4, 256, 0, stream>>>(rowp, ccol, cw, bufA, bufB, 2.f);
    k_gemm<128, 64><<<dim3(800, 1), 128, 0, stream>>>(bufB, w1 + 2 * 128 * 64, b1, H1, H1, 1, 1);

    // Layer 2: 64 -> 64
    k_gemm<64, 64><<<dim3(800, 1), 128, 0, stream>>>(H1, wc2, nullptr, H2, H2, 0, 0);
    k_spmm<64><<<N_NODES / 4, 256, 0, stream>>>(rowp, ccol, cw, H1, bufA, 1.f);
    k_gemm<64, 64><<<dim3(800, 1), 128, 0, stream>>>(bufA, w2 + 64 * 64, nullptr, H2, H2, 1, 0);
    k_spmm<64><<<N_NODES / 4, 256, 0, stream>>>(rowp, ccol, cw, bufA, bufB, 2.f);
    k_gemm<64, 64><<<dim3(800, 1), 128, 0, stream>>>(bufB, w2 + 2 * 64 * 64, b2, H2, H2, 1, 1);

    // Layer 3: 64 -> 128 (output split into H3a / H3b)
    k_gemm<64, 128><<<dim3(800, 2), 128, 0, stream>>>(H2, wc3, nullptr, H3a, H3b, 0, 0);
    k_spmm<64><<<N_NODES / 4, 256, 0, stream>>>(rowp, ccol, cw, H2, bufA, 1.f);
    k_gemm<64, 128><<<dim3(800, 2), 128, 0, stream>>>(bufA, w3 + 64 * 128, nullptr, H3a, H3b, 1, 0);
    k_spmm<64><<<N_NODES / 4, 256, 0, stream>>>(rowp, ccol, cw, bufA, bufB, 2.f);
    k_gemm<64, 128><<<dim3(800, 2), 128, 0, stream>>>(bufB, w3 + 2 * 64 * 128, b3, H3a, H3b, 1, 1);

    // Pool + final linear
    k_pool<<<N_NODES, 128, 0, stream>>>(batch, H3a, H3b, pooled, gcnt);
    k_final<<<N_GRAPHS / 4, 256, 0, stream>>>(pooled, gcnt, lin_w, lin_b, out);
}

// Round 3
// 1651.533 us; speedup vs baseline: 1.7643x; 1.7643x over previous
//
#include <hip/hip_runtime.h>
#include <cstddef>
#include <cstdint>

#define N_NODES 102400
#define N_EDGES 3276800
#define N_GRAPHS 1024

// ---------------------------------------------------------------------------
// CSR build
// ---------------------------------------------------------------------------
__global__ void k_edge_deg(const int* __restrict__ src, const int* __restrict__ dst,
                           const float* __restrict__ w, float* __restrict__ deg,
                           int* __restrict__ cnt) {
    int e = blockIdx.x * blockDim.x + threadIdx.x;
    if (e >= N_EDGES) return;
    atomicAdd(&deg[src[e]], w[e]);
    atomicAdd(&cnt[dst[e]], 1);
}

__global__ void k_dinv(float* __restrict__ deg) {
    int n = blockIdx.x * blockDim.x + threadIdx.x;
    if (n >= N_NODES) return;
    float d = deg[n];
    deg[n] = d > 0.f ? rsqrtf(d) : 0.f;
}

__global__ void k_scan1(const int* __restrict__ cnt, int* __restrict__ bsum) {
    __shared__ int s[256];
    int t = threadIdx.x, b = blockIdx.x;
    int base = b * 1024 + t * 4;
    int v = cnt[base] + cnt[base + 1] + cnt[base + 2] + cnt[base + 3];
    s[t] = v; __syncthreads();
    for (int o = 128; o > 0; o >>= 1) {
        if (t < o) s[t] += s[t + o];
        __syncthreads();
    }
    if (t == 0) bsum[b] = s[0];
}

__global__ void k_scan2(const int* __restrict__ bsum, int* __restrict__ boff,
                        int* __restrict__ rowp) {
    if (threadIdx.x == 0 && blockIdx.x == 0) {
        int run = 0;
        for (int i = 0; i < 100; i++) { boff[i] = run; run += bsum[i]; }
        rowp[N_NODES] = run;
    }
}

__global__ void k_scan3(const int* __restrict__ cnt, const int* __restrict__ boff,
                        int* __restrict__ rowp) {
    __shared__ int ts[256];
    int t = threadIdx.x, b = blockIdx.x;
    int base = b * 1024 + t * 4;
    int v0 = cnt[base], v1 = cnt[base + 1], v2 = cnt[base + 2], v3 = cnt[base + 3];
    int s = v0 + v1 + v2 + v3;
    ts[t] = s; __syncthreads();
    for (int o = 1; o < 256; o <<= 1) {
        int x = (t >= o) ? ts[t - o] : 0;
        __syncthreads();
        ts[t] += x;
        __syncthreads();
    }
    int excl = (t == 0 ? 0 : ts[t - 1]) + boff[b];
    rowp[base]     = excl;
    rowp[base + 1] = excl + v0;
    rowp[base + 2] = excl + v0 + v1;
    rowp[base + 3] = excl + v0 + v1 + v2;
}

__global__ void k_scatter(const int* __restrict__ src, const int* __restrict__ dst,
                          const float* __restrict__ attr, const float* __restrict__ dinv,
                          const int* __restrict__ rowp, int* __restrict__ fill,
                          int2* __restrict__ cedge) {
    int e = blockIdx.x * blockDim.x + threadIdx.x;
    if (e >= N_EDGES) return;
    int s = src[e], d = dst[e];
    float w = -dinv[s] * attr[e] * dinv[d];
    int idx = rowp[d] + atomicAdd(&fill[d], 1);
    cedge[idx] = make_int2(s, __float_as_int(w));
}

// Wcat = [W0 - W2 | W1 | W2]  (fin x 192) from w[3][fin][64]
__global__ void k_wcat(const float* __restrict__ w, float* __restrict__ wcat, int fin) {
    int i = blockIdx.x * blockDim.x + threadIdx.x;
    if (i >= fin * 192) return;
    int r = i / 192, j = i % 192;
    int k = j >> 6, jj = j & 63;
    float v = w[(size_t)k * fin * 64 + r * 64 + jj];
    if (k == 0) v -= w[(size_t)2 * fin * 64 + r * 64 + jj];
    wcat[i] = v;
}

// ---------------------------------------------------------------------------
// SpMM, wave per node, unroll-8 gather pipeline.
// MODE 0: Y = acc
// MODE 1: Y = Aux + 2*acc
// MODE 2: Y = 2*acc - Aux
// MODE 3: Y = relu(Aux + acc + bias[lane])
// ---------------------------------------------------------------------------
template <int MODE, int SX, int SY, int SA>
__global__ __launch_bounds__(256) void k_spmm(const int* __restrict__ rowp,
                                              const int2* __restrict__ cedge,
                                              const float* __restrict__ X,
                                              float* __restrict__ Y,
                                              const float* __restrict__ Aux,
                                              const float* __restrict__ bias) {
    int node = blockIdx.x * 4 + (threadIdx.x >> 6);
    int lane = threadIdx.x & 63;
    int s = rowp[node], e = rowp[node + 1];
    float acc = 0.f;
    int i = s;
    for (; i + 8 <= e; i += 8) {
        int2 ed[8];
#pragma unroll
        for (int u = 0; u < 8; u++) ed[u] = cedge[i + u];
        float v[8];
#pragma unroll
        for (int u = 0; u < 8; u++) v[u] = X[(size_t)ed[u].x * SX + lane];
#pragma unroll
        for (int u = 0; u < 8; u++) acc = fmaf(__int_as_float(ed[u].y), v[u], acc);
    }
    for (; i < e; i++) {
        int2 ed = cedge[i];
        acc = fmaf(__int_as_float(ed.y), X[(size_t)ed.x * SX + lane], acc);
    }
    size_t yoff = (size_t)node * SY + lane;
    if (MODE == 0) {
        Y[yoff] = acc;
    } else if (MODE == 1) {
        Y[yoff] = Aux[(size_t)node * SA + lane] + 2.f * acc;
    } else if (MODE == 2) {
        Y[yoff] = 2.f * acc - Aux[(size_t)node * SA + lane];
    } else {
        Y[yoff] = fmaxf(Aux[(size_t)node * SA + lane] + acc + bias[lane], 0.f);
    }
}

// ---------------------------------------------------------------------------
// GEMM: out[n, colOff + 0..63] = X[n,:] @ W[:, colOff..] (+bias, relu)
// 128 nodes/block, thread-per-node, acc[64] VGPRs, uniform W reads (s_load).
// ---------------------------------------------------------------------------
template <int FIN, int SX, int FTOT, int SOUT, bool RELU>
__global__ __launch_bounds__(128) void k_gemm(const float* __restrict__ X,
                                              const float* __restrict__ W,
                                              const float* __restrict__ bias,
                                              float* __restrict__ out) {
    constexpr int KC = 16;
    __shared__ float Xs[KC][129];
    int t = threadIdx.x;
    int nodeBase = blockIdx.x * 128;
    int colOff = blockIdx.y * 64;
    float acc[64];
#pragma unroll
    for (int j = 0; j < 64; j++) acc[j] = 0.f;
    int kk = t & 15, nl0 = t >> 4;
    for (int k0 = 0; k0 < FIN; k0 += KC) {
        __syncthreads();
#pragma unroll
        for (int r = 0; r < 16; r++) {
            int nl = nl0 + r * 8;
            Xs[kk][nl] = X[(size_t)(nodeBase + nl) * SX + k0 + kk];
        }
        __syncthreads();
#pragma unroll
        for (int i = 0; i < KC; i++) {
            float xv = Xs[i][t];
            const float* wr = W + (size_t)(k0 + i) * FTOT + colOff;
#pragma unroll
            for (int j = 0; j < 64; j++) acc[j] = fmaf(xv, wr[j], acc[j]);
        }
    }
    size_t obase = (size_t)(nodeBase + t) * SOUT + colOff;
    float4* outv = reinterpret_cast<float4*>(out + obase);
#pragma unroll
    for (int j = 0; j < 16; j++) {
        float4 v;
        if (RELU) {
            v.x = fmaxf(acc[4 * j + 0] + bias[colOff + 4 * j + 0], 0.f);
            v.y = fmaxf(acc[4 * j + 1] + bias[colOff + 4 * j + 1], 0.f);
            v.z = fmaxf(acc[4 * j + 2] + bias[colOff + 4 * j + 2], 0.f);
            v.w = fmaxf(acc[4 * j + 3] + bias[colOff + 4 * j + 3], 0.f);
        } else {
            v.x = acc[4 * j + 0]; v.y = acc[4 * j + 1];
            v.z = acc[4 * j + 2]; v.w = acc[4 * j + 3];
        }
        outv[j] = v;
    }
}

// ---------------------------------------------------------------------------
// Pooling: 64 consecutive nodes per block (batch is sorted -> run-length),
// one atomic per (graph-run, column). 128 threads = 128 columns.
// ---------------------------------------------------------------------------
__global__ __launch_bounds__(128) void k_pool(const int* __restrict__ batch,
                                              const float* __restrict__ H3,
                                              float* __restrict__ pooled,
                                              float* __restrict__ gcnt) {
    int t = threadIdx.x;
    int n0 = blockIdx.x * 64;
    int g = batch[n0];
    float a = 0.f;
    int c = 0;
    for (int k = 0; k < 64; k++) {
        int gn = batch[n0 + k];
        if (gn != g) {
            atomicAdd(&pooled[(size_t)g * 128 + t], a);
            if (t == 0) atomicAdd(&gcnt[g], (float)c);
            g = gn; a = 0.f; c = 0;
        }
        a += H3[(size_t)(n0 + k) * 128 + t];
        c++;
    }
    atomicAdd(&pooled[(size_t)g * 128 + t], a);
    if (t == 0) atomicAdd(&gcnt[g], (float)c);
}

__global__ void k_final(const float* __restrict__ pooled, const float* __restrict__ gcnt,
                        const float* __restrict__ lin_w, const float* __restrict__ lin_b,
                        float* __restrict__ out) {
    int g = blockIdx.x * 4 + (threadIdx.x >> 6);
    int lane = threadIdx.x & 63;
    if (g >= N_GRAPHS) return;
    float inv = 1.f / fmaxf(gcnt[g], 1.f);
    float v0 = pooled[(size_t)g * 128 + lane] * inv;
    float v1 = pooled[(size_t)g * 128 + 64 + lane] * inv;
    float p0 = v0 * lin_w[lane * 2 + 0] + v1 * lin_w[(lane + 64) * 2 + 0];
    float p1 = v0 * lin_w[lane * 2 + 1] + v1 * lin_w[(lane + 64) * 2 + 1];
    for (int o = 32; o > 0; o >>= 1) {
        p0 += __shfl_down(p0, o);
        p1 += __shfl_down(p1, o);
    }
    if (lane == 0) {
        out[g * 2 + 0] = p0 + lin_b[0];
        out[g * 2 + 1] = p1 + lin_b[1];
    }
}

// ---------------------------------------------------------------------------
extern "C" void kernel_launch(void* const* d_in, const int* in_sizes, int n_in,
                              void* d_out, int out_size, void* d_ws, size_t ws_size,
                              hipStream_t stream) {
    const float* x     = (const float*)d_in[0];
    const int*   src   = (const int*)d_in[1];
    const int*   dst   = src + N_EDGES;
    const float* eattr = (const float*)d_in[2];
    const int*   batch = (const int*)d_in[3];
    const float* w1    = (const float*)d_in[4];
    const float* b1    = (const float*)d_in[5];
    const float* w2    = (const float*)d_in[6];
    const float* b2    = (const float*)d_in[7];
    const float* w3    = (const float*)d_in[8];
    const float* b3    = (const float*)d_in[9];
    const float* lin_w = (const float*)d_in[10];
    const float* lin_b = (const float*)d_in[11];
    float* out = (float*)d_out;

    char* ws = (char*)d_ws;
    size_t off = 0;
    auto alloc = [&](size_t bytes) -> char* {
        char* p = ws + off;
        off += (bytes + 255) & ~(size_t)255;
        return p;
    };
    float* deg    = (float*)alloc((size_t)N_NODES * 4);   // deg -> dinv in place
    int*   cnt    = (int*)  alloc((size_t)N_NODES * 4);
    int*   fill   = (int*)  alloc((size_t)N_NODES * 4);
    int*   rowp   = (int*)  alloc((size_t)(N_NODES + 1) * 4);
    int*   bsum   = (int*)  alloc(128 * 4);
    int*   boff   = (int*)  alloc(128 * 4);
    float* wcat1  = (float*)alloc(128 * 192 * 4);
    float* wcat2  = (float*)alloc(64 * 192 * 4);
    float* pooled = (float*)alloc((size_t)(N_GRAPHS * 128 + N_GRAPHS) * 4);
    float* gcnt   = pooled + (size_t)N_GRAPHS * 128;
    int2*  cedge  = (int2*) alloc((size_t)N_EDGES * 8);
    float* P      = (float*)alloc((size_t)N_NODES * 192 * 4);  // [P0c|P1|P2] / [T0|T1|T2]
    float* H1     = (float*)alloc((size_t)N_NODES * 128 * 4);  // layer-1 out (N x 64); H3 aliases (N x 128)
    float* H3     = H1;

    hipMemsetAsync(deg, 0, (size_t)N_NODES * 4 * 3, stream);  // deg, cnt, fill contiguous
    hipMemsetAsync(pooled, 0, (size_t)(N_GRAPHS * 128 + N_GRAPHS) * 4, stream);

    // CSR build
    k_edge_deg<<<N_EDGES / 256, 256, 0, stream>>>(src, dst, eattr, deg, cnt);
    k_dinv<<<N_NODES / 256, 256, 0, stream>>>(deg);
    k_scan1<<<100, 256, 0, stream>>>(cnt, bsum);
    k_scan2<<<1, 64, 0, stream>>>(bsum, boff, rowp);
    k_scan3<<<100, 256, 0, stream>>>(cnt, boff, rowp);
    k_scatter<<<N_EDGES / 256, 256, 0, stream>>>(src, dst, eattr, deg, rowp, fill, cedge);

    // concatenated weights for project-first layers
    k_wcat<<<(128 * 192 + 255) / 256, 256, 0, stream>>>(w1, wcat1, 128);
    k_wcat<<<(64 * 192 + 255) / 256, 256, 0, stream>>>(w2, wcat2, 64);

    // ---- Layer 1 (128 -> 64), project-first: P = x @ [W0-W2|W1|W2]
    k_gemm<128, 128, 192, 192, false><<<dim3(800, 3), 128, 0, stream>>>(x, wcat1, nullptr, P);
    // Q = P1 + 2*L*P2  (gather slot2, write slot1 in place)
    k_spmm<1, 192, 192, 192><<<N_NODES / 4, 256, 0, stream>>>(rowp, cedge, P + 128, P + 64, P + 64, nullptr);
    // H1 = relu(P0c + L*Q + b1)
    k_spmm<3, 192, 64, 192><<<N_NODES / 4, 256, 0, stream>>>(rowp, cedge, P + 64, H1, P, b1);

    // ---- Layer 2 (64 -> 64)
    k_gemm<64, 64, 192, 192, false><<<dim3(800, 3), 128, 0, stream>>>(H1, wcat2, nullptr, P);
    k_spmm<1, 192, 192, 192><<<N_NODES / 4, 256, 0, stream>>>(rowp, cedge, P + 128, P + 64, P + 64, nullptr);
    // write layer-2 output into P slot0 (in place over P0c; others gather slot1 only)
    k_spmm<3, 192, 192, 192><<<N_NODES / 4, 256, 0, stream>>>(rowp, cedge, P + 64, P, P, b2);

    // ---- Layer 3 (64 -> 128), spmm-first: T0 = P slot0
    // T1 = L*T0 -> slot1
    k_spmm<0, 192, 192, 192><<<N_NODES / 4, 256, 0, stream>>>(rowp, cedge, P, P + 64, nullptr, nullptr);
    // T2 = 2*L*T1 - T0 -> slot2
    k_spmm<2, 192, 192, 192><<<N_NODES / 4, 256, 0, stream>>>(rowp, cedge, P + 64, P + 128, P, nullptr);
    // H3 = relu([T0|T1|T2] @ w3_flat + b3)   (w3 is [3][64][128] = [192][128] row-major)
    k_gemm<192, 192, 128, 128, true><<<dim3(800, 2), 128, 0, stream>>>(P, w3, b3, H3);

    // ---- Pool + final linear
    k_pool<<<N_NODES / 64, 128, 0, stream>>>(batch, H3, pooled, gcnt);
    k_final<<<N_GRAPHS / 4, 256, 0, stream>>>(pooled, gcnt, lin_w, lin_b, out);
}

// Round 4
// 1510.718 us; speedup vs baseline: 1.9287x; 1.0932x over previous
//
#include <hip/hip_runtime.h>
#include <cstddef>
#include <cstdint>

#define N_NODES 102400
#define N_EDGES 3276800
#define N_GRAPHS 1024

typedef unsigned short ushortT;
typedef unsigned int uintT;

__device__ __forceinline__ float b2f(ushortT h) {
    return __uint_as_float(((uintT)h) << 16);
}
__device__ __forceinline__ ushortT f2b(float f) {
    uintT u = __float_as_uint(f);
    uintT r = (u + 0x7fffu + ((u >> 16) & 1u)) >> 16;
    return (ushortT)r;
}

// ---------------------------------------------------------------------------
// Histogram pass: 8-way replicated deg (by src, weighted) and cnt (by dst),
// copy index = blockIdx & 7. rank[e] = per-copy rank among same-dst edges.
// ---------------------------------------------------------------------------
__global__ __launch_bounds__(256) void k_hist(const int* __restrict__ src,
                                              const int* __restrict__ dst,
                                              const float* __restrict__ attr,
                                              float* __restrict__ deg8,
                                              int* __restrict__ cnt8,
                                              int* __restrict__ rank) {
    int e = blockIdx.x * 256 + threadIdx.x;
    int copy = blockIdx.x & 7;
    atomicAdd(&deg8[copy * N_NODES + src[e]], attr[e]);
    rank[e] = atomicAdd(&cnt8[copy * N_NODES + dst[e]], 1);
}

// Reduce 8 copies: dinv = rsqrt(sum deg8), cnt = sum cnt8, base8 = excl prefix
__global__ __launch_bounds__(256) void k_reduce(const float* __restrict__ deg8,
                                                const int* __restrict__ cnt8,
                                                float* __restrict__ dinv,
                                                int* __restrict__ base8,
                                                int* __restrict__ cnt) {
    int n = blockIdx.x * 256 + threadIdx.x;
    if (n >= N_NODES) return;
    float d = 0.f;
    int run = 0;
#pragma unroll
    for (int c = 0; c < 8; c++) {
        d += deg8[c * N_NODES + n];
        base8[c * N_NODES + n] = run;
        run += cnt8[c * N_NODES + n];
    }
    cnt[n] = run;
    dinv[n] = d > 0.f ? rsqrtf(d) : 0.f;
}

// 3-kernel exclusive scan of cnt[N_NODES] -> rowp[N_NODES+1]
__global__ void k_scan1(const int* __restrict__ cnt, int* __restrict__ bsum) {
    __shared__ int s[256];
    int t = threadIdx.x, b = blockIdx.x;
    int base = b * 1024 + t * 4;
    int v = cnt[base] + cnt[base + 1] + cnt[base + 2] + cnt[base + 3];
    s[t] = v; __syncthreads();
    for (int o = 128; o > 0; o >>= 1) {
        if (t < o) s[t] += s[t + o];
        __syncthreads();
    }
    if (t == 0) bsum[b] = s[0];
}

__global__ void k_scan2(const int* __restrict__ bsum, int* __restrict__ boff,
                        int* __restrict__ rowp) {
    if (threadIdx.x == 0 && blockIdx.x == 0) {
        int run = 0;
        for (int i = 0; i < 100; i++) { boff[i] = run; run += bsum[i]; }
        rowp[N_NODES] = run;
    }
}

__global__ void k_scan3(const int* __restrict__ cnt, const int* __restrict__ boff,
                        int* __restrict__ rowp) {
    __shared__ int ts[256];
    int t = threadIdx.x, b = blockIdx.x;
    int base = b * 1024 + t * 4;
    int v0 = cnt[base], v1 = cnt[base + 1], v2 = cnt[base + 2], v3 = cnt[base + 3];
    int s = v0 + v1 + v2 + v3;
    ts[t] = s; __syncthreads();
    for (int o = 1; o < 256; o <<= 1) {
        int x = (t >= o) ? ts[t - o] : 0;
        __syncthreads();
        ts[t] += x;
        __syncthreads();
    }
    int excl = (t == 0 ? 0 : ts[t - 1]) + boff[b];
    rowp[base]     = excl;
    rowp[base + 1] = excl + v0;
    rowp[base + 2] = excl + v0 + v1;
    rowp[base + 3] = excl + v0 + v1 + v2;
}

// Atomic-free scatter: idx = rowp[d] + base8[copy][d] + rank[e]
__global__ __launch_bounds__(256) void k_scatter2(const int* __restrict__ src,
                                                  const int* __restrict__ dst,
                                                  const float* __restrict__ attr,
                                                  const float* __restrict__ dinv,
                                                  const int* __restrict__ rowp,
                                                  const int* __restrict__ base8,
                                                  const int* __restrict__ rank,
                                                  int2* __restrict__ cedge) {
    int e = blockIdx.x * 256 + threadIdx.x;
    int copy = blockIdx.x & 7;
    int s = src[e], d = dst[e];
    float w = -dinv[s] * attr[e] * dinv[d];
    int idx = rowp[d] + base8[copy * N_NODES + d] + rank[e];
    cedge[idx] = make_int2(s, __float_as_int(w));
}

// Wcat = [W0 - W2 | W1 | W2]  (fin x 192) from w[3][fin][64]
__global__ void k_wcat(const float* __restrict__ w, float* __restrict__ wcat, int fin) {
    int i = blockIdx.x * blockDim.x + threadIdx.x;
    if (i >= fin * 192) return;
    int r = i / 192, j = i % 192;
    int k = j >> 6, jj = j & 63;
    float v = w[(size_t)k * fin * 64 + r * 64 + jj];
    if (k == 0) v -= w[(size_t)2 * fin * 64 + r * 64 + jj];
    wcat[i] = v;
}

// ---------------------------------------------------------------------------
// SpMM: gathers bf16 rows (stride 64), fp32 accumulate, unroll-8 pipeline.
// MODE 0: r = acc          MODE 1: r = Aux + 2*acc
// MODE 2: r = 2*acc - Aux  MODE 3: r = relu(Aux + acc + bias[lane])
// Optional bf16 mirror of the result (WB).
// ---------------------------------------------------------------------------
template <int MODE, int SY, int SA, bool WB>
__global__ __launch_bounds__(256) void k_spmm(const int* __restrict__ rowp,
                                              const int2* __restrict__ cedge,
                                              const ushortT* __restrict__ Xb,
                                              float* __restrict__ Y,
                                              const float* __restrict__ Aux,
                                              const float* __restrict__ bias,
                                              ushortT* __restrict__ Yb) {
    int node = blockIdx.x * 4 + (threadIdx.x >> 6);
    int lane = threadIdx.x & 63;
    int s = rowp[node], e = rowp[node + 1];
    float acc = 0.f;
    int i = s;
    for (; i + 8 <= e; i += 8) {
        int2 ed[8];
#pragma unroll
        for (int u = 0; u < 8; u++) ed[u] = cedge[i + u];
        float v[8];
#pragma unroll
        for (int u = 0; u < 8; u++) v[u] = b2f(Xb[(size_t)ed[u].x * 64 + lane]);
#pragma unroll
        for (int u = 0; u < 8; u++) acc = fmaf(__int_as_float(ed[u].y), v[u], acc);
    }
    for (; i < e; i++) {
        int2 ed = cedge[i];
        acc = fmaf(__int_as_float(ed.y), b2f(Xb[(size_t)ed.x * 64 + lane]), acc);
    }
    float r;
    if (MODE == 0)      r = acc;
    else if (MODE == 1) r = Aux[(size_t)node * SA + lane] + 2.f * acc;
    else if (MODE == 2) r = 2.f * acc - Aux[(size_t)node * SA + lane];
    else                r = fmaxf(Aux[(size_t)node * SA + lane] + acc + bias[lane], 0.f);
    Y[(size_t)node * SY + lane] = r;
    if (WB) Yb[(size_t)node * 64 + lane] = f2b(r);
}

// ---------------------------------------------------------------------------
// GEMM: out[n, colOff + 0..63] = X[n,:] @ W[:, colOff..] (+bias, relu)
// 128 nodes/block, thread-per-node, acc[64] VGPRs, uniform W reads (s_load).
// BSLOT >= 0: blocks with colOff == BSLOT also write a bf16 mirror (stride 64).
// ---------------------------------------------------------------------------
template <int FIN, int SX, int FTOT, int SOUT, bool RELU, int BSLOT>
__global__ __launch_bounds__(128) void k_gemm(const float* __restrict__ X,
                                              const float* __restrict__ W,
                                              const float* __restrict__ bias,
                                              float* __restrict__ out,
                                              ushortT* __restrict__ bout) {
    constexpr int KC = 16;
    __shared__ float Xs[KC][129];
    int t = threadIdx.x;
    int nodeBase = blockIdx.x * 128;
    int colOff = blockIdx.y * 64;
    float acc[64];
#pragma unroll
    for (int j = 0; j < 64; j++) acc[j] = 0.f;
    int kk = t & 15, nl0 = t >> 4;
    for (int k0 = 0; k0 < FIN; k0 += KC) {
        __syncthreads();
#pragma unroll
        for (int r = 0; r < 16; r++) {
            int nl = nl0 + r * 8;
            Xs[kk][nl] = X[(size_t)(nodeBase + nl) * SX + k0 + kk];
        }
        __syncthreads();
#pragma unroll
        for (int i = 0; i < KC; i++) {
            float xv = Xs[i][t];
            const float* wr = W + (size_t)(k0 + i) * FTOT + colOff;
#pragma unroll
            for (int j = 0; j < 64; j++) acc[j] = fmaf(xv, wr[j], acc[j]);
        }
    }
    size_t obase = (size_t)(nodeBase + t) * SOUT + colOff;
    float4* outv = reinterpret_cast<float4*>(out + obase);
#pragma unroll
    for (int j = 0; j < 16; j++) {
        float4 v;
        if (RELU) {
            v.x = fmaxf(acc[4 * j + 0] + bias[colOff + 4 * j + 0], 0.f);
            v.y = fmaxf(acc[4 * j + 1] + bias[colOff + 4 * j + 1], 0.f);
            v.z = fmaxf(acc[4 * j + 2] + bias[colOff + 4 * j + 2], 0.f);
            v.w = fmaxf(acc[4 * j + 3] + bias[colOff + 4 * j + 3], 0.f);
        } else {
            v.x = acc[4 * j + 0]; v.y = acc[4 * j + 1];
            v.z = acc[4 * j + 2]; v.w = acc[4 * j + 3];
        }
        outv[j] = v;
    }
    if (BSLOT >= 0 && colOff == BSLOT) {
        ushort4* bv = reinterpret_cast<ushort4*>(bout + (size_t)(nodeBase + t) * 64);
#pragma unroll
        for (int j = 0; j < 16; j++) {
            ushort4 h;
            h.x = f2b(acc[4 * j + 0]);
            h.y = f2b(acc[4 * j + 1]);
            h.z = f2b(acc[4 * j + 2]);
            h.w = f2b(acc[4 * j + 3]);
            bv[j] = h;
        }
    }
}

// ---------------------------------------------------------------------------
// Pooling: 64 consecutive nodes per block (batch sorted -> run-length),
// one atomic per (graph-run, column). 128 threads = 128 columns.
// ---------------------------------------------------------------------------
__global__ __launch_bounds__(128) void k_pool(const int* __restrict__ batch,
                                              const float* __restrict__ H3,
                                              float* __restrict__ pooled,
                                              float* __restrict__ gcnt) {
    int t = threadIdx.x;
    int n0 = blockIdx.x * 64;
    int g = batch[n0];
    float a = 0.f;
    int c = 0;
    for (int k = 0; k < 64; k++) {
        int gn = batch[n0 + k];
        if (gn != g) {
            atomicAdd(&pooled[(size_t)g * 128 + t], a);
            if (t == 0) atomicAdd(&gcnt[g], (float)c);
            g = gn; a = 0.f; c = 0;
        }
        a += H3[(size_t)(n0 + k) * 128 + t];
        c++;
    }
    atomicAdd(&pooled[(size_t)g * 128 + t], a);
    if (t == 0) atomicAdd(&gcnt[g], (float)c);
}

__global__ void k_final(const float* __restrict__ pooled, const float* __restrict__ gcnt,
                        const float* __restrict__ lin_w, const float* __restrict__ lin_b,
                        float* __restrict__ out) {
    int g = blockIdx.x * 4 + (threadIdx.x >> 6);
    int lane = threadIdx.x & 63;
    if (g >= N_GRAPHS) return;
    float inv = 1.f / fmaxf(gcnt[g], 1.f);
    float v0 = pooled[(size_t)g * 128 + lane] * inv;
    float v1 = pooled[(size_t)g * 128 + 64 + lane] * inv;
    float p0 = v0 * lin_w[lane * 2 + 0] + v1 * lin_w[(lane + 64) * 2 + 0];
    float p1 = v0 * lin_w[lane * 2 + 1] + v1 * lin_w[(lane + 64) * 2 + 1];
    for (int o = 32; o > 0; o >>= 1) {
        p0 += __shfl_down(p0, o);
        p1 += __shfl_down(p1, o);
    }
    if (lane == 0) {
        out[g * 2 + 0] = p0 + lin_b[0];
        out[g * 2 + 1] = p1 + lin_b[1];
    }
}

// ---------------------------------------------------------------------------
extern "C" void kernel_launch(void* const* d_in, const int* in_sizes, int n_in,
                              void* d_out, int out_size, void* d_ws, size_t ws_size,
                              hipStream_t stream) {
    const float* x     = (const float*)d_in[0];
    const int*   src   = (const int*)d_in[1];
    const int*   dst   = src + N_EDGES;
    const float* eattr = (const float*)d_in[2];
    const int*   batch = (const int*)d_in[3];
    const float* w1    = (const float*)d_in[4];
    const float* b1    = (const float*)d_in[5];
    const float* w2    = (const float*)d_in[6];
    const float* b2    = (const float*)d_in[7];
    const float* w3    = (const float*)d_in[8];
    const float* b3    = (const float*)d_in[9];
    const float* lin_w = (const float*)d_in[10];
    const float* lin_b = (const float*)d_in[11];
    float* out = (float*)d_out;

    char* ws = (char*)d_ws;
    size_t off = 0;
    auto alloc = [&](size_t bytes) -> char* {
        char* p = ws + off;
        off += (bytes + 255) & ~(size_t)255;
        return p;
    };
    float* deg8   = (float*)alloc((size_t)8 * N_NODES * 4);   // 3.28 MB
    int*   cnt8   = (int*)  alloc((size_t)8 * N_NODES * 4);   // 3.28 MB (contiguous w/ deg8)
    int*   base8  = (int*)  alloc((size_t)8 * N_NODES * 4);
    int*   rank   = (int*)  alloc((size_t)N_EDGES * 4);       // 13.1 MB
    float* dinv   = (float*)alloc((size_t)N_NODES * 4);
    int*   cnt    = (int*)  alloc((size_t)N_NODES * 4);
    int*   rowp   = (int*)  alloc((size_t)(N_NODES + 1) * 4);
    int*   bsum   = (int*)  alloc(128 * 4);
    int*   boff   = (int*)  alloc(128 * 4);
    float* wcat1  = (float*)alloc(128 * 192 * 4);
    float* wcat2  = (float*)alloc(64 * 192 * 4);
    float* pooled = (float*)alloc((size_t)(N_GRAPHS * 128 + N_GRAPHS) * 4);
    float* gcnt   = pooled + (size_t)N_GRAPHS * 128;
    int2*  cedge  = (int2*) alloc((size_t)N_EDGES * 8);        // 26.2 MB
    float* P      = (float*)alloc((size_t)N_NODES * 192 * 4);  // 78.6 MB
    float* H      = (float*)alloc((size_t)N_NODES * 128 * 4);  // 52.4 MB: H1 (stride 64) lower; H3 full
    // bf16 gather tables alias H's upper half (dead until the L3 GEMM writes H3,
    // by which time G0/G1 are no longer needed)
    ushortT* G0 = (ushortT*)(H + (size_t)N_NODES * 64);        // 13.1 MB
    ushortT* G1 = G0 + (size_t)N_NODES * 64;                   // 13.1 MB

    hipMemsetAsync(deg8, 0, (size_t)8 * N_NODES * 4 * 2, stream);  // deg8 + cnt8
    hipMemsetAsync(pooled, 0, (size_t)(N_GRAPHS * 128 + N_GRAPHS) * 4, stream);

    // CSR build (replicated histograms, atomic-free scatter)
    k_hist<<<N_EDGES / 256, 256, 0, stream>>>(src, dst, eattr, deg8, cnt8, rank);
    k_reduce<<<N_NODES / 256, 256, 0, stream>>>(deg8, cnt8, dinv, base8, cnt);
    k_scan1<<<100, 256, 0, stream>>>(cnt, bsum);
    k_scan2<<<1, 64, 0, stream>>>(bsum, boff, rowp);
    k_scan3<<<100, 256, 0, stream>>>(cnt, boff, rowp);
    k_scatter2<<<N_EDGES / 256, 256, 0, stream>>>(src, dst, eattr, dinv, rowp, base8, rank, cedge);

    // concatenated weights for project-first layers
    k_wcat<<<(128 * 192 + 255) / 256, 256, 0, stream>>>(w1, wcat1, 128);
    k_wcat<<<(64 * 192 + 255) / 256, 256, 0, stream>>>(w2, wcat2, 64);

    // ---- Layer 1 (128 -> 64): P = x @ [W0-W2|W1|W2], mirror P2 -> G0
    k_gemm<128, 128, 192, 192, false, 128><<<dim3(800, 3), 128, 0, stream>>>(x, wcat1, nullptr, P, G0);
    // Q = P1 + 2*L*P2 -> P+64 (fp32) and G1 (bf16)
    k_spmm<1, 192, 192, true><<<N_NODES / 4, 256, 0, stream>>>(rowp, cedge, G0, P + 64, P + 64, nullptr, G1);
    // H1 = relu(P0c + L*Q + b1) -> H (stride 64)
    k_spmm<3, 64, 192, false><<<N_NODES / 4, 256, 0, stream>>>(rowp, cedge, G1, H, P, b1, nullptr);

    // ---- Layer 2 (64 -> 64)
    k_gemm<64, 64, 192, 192, false, 128><<<dim3(800, 3), 128, 0, stream>>>(H, wcat2, nullptr, P, G0);
    k_spmm<1, 192, 192, true><<<N_NODES / 4, 256, 0, stream>>>(rowp, cedge, G0, P + 64, P + 64, nullptr, G1);
    // T0 = relu(...) -> P slot0 (fp32) and G0 (bf16)
    k_spmm<3, 192, 192, true><<<N_NODES / 4, 256, 0, stream>>>(rowp, cedge, G1, P, P, b2, G0);

    // ---- Layer 3 (64 -> 128), spmm-first
    // T1 = L*T0 -> P+64 (fp32) and G1 (bf16)
    k_spmm<0, 192, 192, true><<<N_NODES / 4, 256, 0, stream>>>(rowp, cedge, G0, P + 64, P, nullptr, G1);
    // T2 = 2*L*T1 - T0 -> P+128
    k_spmm<2, 192, 192, false><<<N_NODES / 4, 256, 0, stream>>>(rowp, cedge, G1, P + 128, P, nullptr, nullptr);
    // H3 = relu([T0|T1|T2] @ w3_flat + b3) -> H (stride 128; clobbers G0/G1 - dead)
    k_gemm<192, 192, 128, 128, true, -1><<<dim3(800, 2), 128, 0, stream>>>(P, w3, b3, H, nullptr);

    // ---- Pool + final linear
    k_pool<<<N_NODES / 64, 128, 0, stream>>>(batch, H, pooled, gcnt);
    k_final<<<N_GRAPHS / 4, 256, 0, stream>>>(pooled, gcnt, lin_w, lin_b, out);
}